// Round 1
// baseline (567.840 us; speedup 1.0000x reference)
//
#include <hip/hip_runtime.h>
#include <hip/hip_bf16.h>
#include <stdint.h>

#define BATCH 16384
#define FACE_K 64
#define VISUAL_DIM 2048
#define HIDDEN 512
#define NUM_USERS 1000000
#define NUM_AGES 8
#define NUM_ATTR 40
#define VOCAB (NUM_USERS + 24 + 2 + NUM_AGES + NUM_ATTR)
#define XDIM 384
#define XS 388    // x-tile LDS stride (pad +4)
#define HS 516    // h1 LDS stride (pad +4)

typedef __bf16 bf16x8 __attribute__((ext_vector_type(8)));
typedef float f32x4 __attribute__((ext_vector_type(4)));

__device__ __forceinline__ uint16_t f2bf(float f) {
    union { float f; uint32_t u; } v; v.f = f;
    uint32_t r = v.u + 0x7fffu + ((v.u >> 16) & 1u);
    return (uint16_t)(r >> 16);
}

// fp32x8 -> bf16x8 in registers (compiler emits v_cvt_pk_bf16_f32 pairs)
__device__ __forceinline__ bf16x8 cvt8(float4 a, float4 b) {
    bf16x8 r;
    r[0] = (__bf16)a.x; r[1] = (__bf16)a.y; r[2] = (__bf16)a.z; r[3] = (__bf16)a.w;
    r[4] = (__bf16)b.x; r[5] = (__bf16)b.y; r[6] = (__bf16)b.z; r[7] = (__bf16)b.w;
    return r;
}

// ---------------- mega-kernel: 32 rows per block, end-to-end, NO workspace ----------------
// 4 waves / block, grid = BATCH/32 = 512 blocks (2 blocks/CU)
__global__ __launch_bounds__(256) void mega_kernel(
        const int* __restrict__ uid, const int* __restrict__ hour,
        const float* __restrict__ visual, const float* __restrict__ scale,
        const int* __restrict__ gender, const int* __restrict__ age,
        const int* __restrict__ attr,
        const float* __restrict__ user_emb, const float* __restrict__ hour_emb,
        const float* __restrict__ gender_emb, const float* __restrict__ age_emb,
        const float* __restrict__ attr_emb,
        const float* __restrict__ visu_w, const float* __restrict__ visu_b,
        const float* __restrict__ fm_w, const float* __restrict__ fm_b,
        const float* __restrict__ w1, const float* __restrict__ b1,
        const float* __restrict__ w2, const float* __restrict__ b2,
        const float* __restrict__ w3, const float* __restrict__ b3,
        float* __restrict__ out) {
    __shared__ uint16_t x_tile[32 * XS];
    __shared__ uint16_t h1s[32 * HS];
    __shared__ float red[2][16 * 64];
    __shared__ float fm_s[32][2];
    __shared__ float dred[4][32][2];

    int t = threadIdx.x;
    int wv = t >> 6, lane = t & 63;
    int lc = lane & 15, quad = lane >> 4;
    int m0 = blockIdx.x * 32;

    // ================= Phase E: embeddings + FM (wave -> 8 rows) =================
    {
        #pragma unroll 2
        for (int r8 = 0; r8 < 8; ++r8) {
            int row_l = wv * 8 + r8;
            int row_g = m0 + row_l;
            int u = uid[row_g], h = hour[row_g], g = gender[row_g];
            int a = age[row_g], at = attr[row_g];
            float sc = scale[row_g];
            float eu  = user_emb[(size_t)u * 64 + lane];
            float eh  = hour_emb[h * 64 + lane];
            float eg  = sc * tanhf(gender_emb[g * 64 + lane]);
            float eat = sc * tanhf(attr_emb[at * 64 + lane]);
            float eag = sc * tanhf(age_emb[a * 64 + lane]);
            float s  = eu + eh + eg + eat + eag;
            float sq = eu*eu + eh*eh + eg*eg + eat*eat + eag*eag;
            float so = s * s - sq;
            float l0 = 0.f, l1 = 0.f;
            if (lane < 5) {
                int col = (lane == 0) ? u
                        : (lane == 1) ? (NUM_USERS + h)
                        : (lane == 2) ? (NUM_USERS + 24 + g)
                        : (lane == 3) ? (NUM_USERS + 26 + a)
                        :               (NUM_USERS + 34 + at);
                l0 = fm_w[col];
                l1 = fm_w[VOCAB + col];
            }
            for (int m = 32; m; m >>= 1) {
                so += __shfl_xor(so, m);
                l0 += __shfl_xor(l0, m);
                l1 += __shfl_xor(l1, m);
            }
            if (lane == 0) {
                fm_s[row_l][0] = l0 + fm_b[0] + 0.5f * so;
                fm_s[row_l][1] = l1 + fm_b[1] + 0.5f * so;
            }
            int xb = row_l * XS;
            x_tile[xb +       lane] = f2bf(eu);
            x_tile[xb +  64 + lane] = f2bf(eh);
            x_tile[xb + 128 + lane] = f2bf(eg);
            x_tile[xb + 192 + lane] = f2bf(eat);
            x_tile[xb + 256 + lane] = f2bf(eag);
        }
    }

    // ================= Phase V: visual projection (wave = rg x kh) =================
    {
        int rg = wv >> 1, kh = wv & 1;
        const float* va = visual + (size_t)(m0 + rg * 16 + lc) * VISUAL_DIM + kh * 1024 + quad * 8;
        const float* vb = visu_w + (size_t)lc * VISUAL_DIM + kh * 1024 + quad * 8;

        f32x4 acc[4];
        #pragma unroll
        for (int j = 0; j < 4; ++j) acc[j] = (f32x4){0.f, 0.f, 0.f, 0.f};

        #pragma unroll 2
        for (int k = 0; k < 1024; k += 32) {
            float4 a0 = *(const float4*)(va + k);
            float4 a1 = *(const float4*)(va + k + 4);
            bf16x8 af = cvt8(a0, a1);
            #pragma unroll
            for (int j = 0; j < 4; ++j) {
                float4 b0 = *(const float4*)(vb + (size_t)(j * 16) * VISUAL_DIM + k);
                float4 b1 = *(const float4*)(vb + (size_t)(j * 16) * VISUAL_DIM + k + 4);
                acc[j] = __builtin_amdgcn_mfma_f32_16x16x32_bf16(af, cvt8(b0, b1), acc[j], 0, 0, 0);
            }
        }
        if (kh == 1) {
            #pragma unroll
            for (int j = 0; j < 4; ++j)
                #pragma unroll
                for (int r = 0; r < 4; ++r)
                    red[rg][(quad * 4 + r) * 64 + j * 16 + lc] = acc[j][r];
        }
        __syncthreads();
        if (kh == 0) {
            #pragma unroll
            for (int j = 0; j < 4; ++j) {
                int col = j * 16 + lc;
                float b = visu_b[col];
                #pragma unroll
                for (int r = 0; r < 4; ++r) {
                    float sum = acc[j][r] + red[rg][(quad * 4 + r) * 64 + col] + b;
                    x_tile[(rg * 16 + quad * 4 + r) * XS + 320 + col] = f2bf(sum);
                }
            }
        }
    }
    __syncthreads();

    // ================= Phase 1: h1 = relu(x @ w1^T + b1), wave = col-quarter ======
    {
        int cs = wv;  // cols cs*128 .. cs*128+127
        const float* wp1 = w1 + (size_t)(cs * 128 + lc) * XDIM + quad * 8;
        const uint16_t* lp0 = x_tile + lc * XS + quad * 8;
        const uint16_t* lp1 = x_tile + (16 + lc) * XS + quad * 8;

        f32x4 acc[2][8];
        #pragma unroll
        for (int i = 0; i < 2; ++i)
            #pragma unroll
            for (int j = 0; j < 8; ++j) acc[i][j] = (f32x4){0.f, 0.f, 0.f, 0.f};

        #pragma unroll 2
        for (int ks = 0; ks < 12; ++ks) {
            union { bf16x8 v; ushort4 h[2]; } u0, u1;
            u0.h[0] = *(const ushort4*)(lp0 + ks * 32);
            u0.h[1] = *(const ushort4*)(lp0 + ks * 32 + 4);
            u1.h[0] = *(const ushort4*)(lp1 + ks * 32);
            u1.h[1] = *(const ushort4*)(lp1 + ks * 32 + 4);
            #pragma unroll
            for (int j = 0; j < 8; ++j) {
                float4 c0 = *(const float4*)(wp1 + (size_t)(j * 16) * XDIM + ks * 32);
                float4 c1 = *(const float4*)(wp1 + (size_t)(j * 16) * XDIM + ks * 32 + 4);
                bf16x8 bf = cvt8(c0, c1);
                acc[0][j] = __builtin_amdgcn_mfma_f32_16x16x32_bf16(u0.v, bf, acc[0][j], 0, 0, 0);
                acc[1][j] = __builtin_amdgcn_mfma_f32_16x16x32_bf16(u1.v, bf, acc[1][j], 0, 0, 0);
            }
        }
        #pragma unroll
        for (int j = 0; j < 8; ++j) {
            int col = cs * 128 + j * 16 + lc;
            float bb = b1[col];
            #pragma unroll
            for (int i = 0; i < 2; ++i)
                #pragma unroll
                for (int r = 0; r < 4; ++r) {
                    float v = fmaxf(acc[i][j][r] + bb, 0.f);
                    h1s[(i * 16 + quad * 4 + r) * HS + col] = f2bf(v);
                }
        }
    }
    __syncthreads();

    // ================= Phase 2: h2 cols + w3-dot + softmax =================
    {
        int cs = wv;
        const float* wp2 = w2 + (size_t)(cs * 128 + lc) * HIDDEN + quad * 8;
        const uint16_t* lp0 = h1s + lc * HS + quad * 8;
        const uint16_t* lp1 = h1s + (16 + lc) * HS + quad * 8;

        f32x4 acc[2][8];
        #pragma unroll
        for (int i = 0; i < 2; ++i)
            #pragma unroll
            for (int j = 0; j < 8; ++j) acc[i][j] = (f32x4){0.f, 0.f, 0.f, 0.f};

        #pragma unroll 2
        for (int ks = 0; ks < 16; ++ks) {
            union { bf16x8 v; ushort4 h[2]; } u0, u1;
            u0.h[0] = *(const ushort4*)(lp0 + ks * 32);
            u0.h[1] = *(const ushort4*)(lp0 + ks * 32 + 4);
            u1.h[0] = *(const ushort4*)(lp1 + ks * 32);
            u1.h[1] = *(const ushort4*)(lp1 + ks * 32 + 4);
            #pragma unroll
            for (int j = 0; j < 8; ++j) {
                float4 c0 = *(const float4*)(wp2 + (size_t)(j * 16) * HIDDEN + ks * 32);
                float4 c1 = *(const float4*)(wp2 + (size_t)(j * 16) * HIDDEN + ks * 32 + 4);
                bf16x8 bf = cvt8(c0, c1);
                acc[0][j] = __builtin_amdgcn_mfma_f32_16x16x32_bf16(u0.v, bf, acc[0][j], 0, 0, 0);
                acc[1][j] = __builtin_amdgcn_mfma_f32_16x16x32_bf16(u1.v, bf, acc[1][j], 0, 0, 0);
            }
        }
        // relu + b2, dot with w3 columns
        float d0[2][4] = {{0,0,0,0},{0,0,0,0}}, d1[2][4] = {{0,0,0,0},{0,0,0,0}};
        #pragma unroll
        for (int j = 0; j < 8; ++j) {
            int col = cs * 128 + j * 16 + lc;
            float bb = b2[col];
            float wa = w3[col], wb = w3[HIDDEN + col];
            #pragma unroll
            for (int i = 0; i < 2; ++i)
                #pragma unroll
                for (int r = 0; r < 4; ++r) {
                    float v = fmaxf(acc[i][j][r] + bb, 0.f);
                    d0[i][r] += v * wa;
                    d1[i][r] += v * wb;
                }
        }
        #pragma unroll
        for (int m = 1; m <= 8; m <<= 1) {
            #pragma unroll
            for (int i = 0; i < 2; ++i)
                #pragma unroll
                for (int r = 0; r < 4; ++r) {
                    d0[i][r] += __shfl_xor(d0[i][r], m);
                    d1[i][r] += __shfl_xor(d1[i][r], m);
                }
        }
        if (lc == 0) {
            #pragma unroll
            for (int i = 0; i < 2; ++i)
                #pragma unroll
                for (int r = 0; r < 4; ++r) {
                    dred[cs][i * 16 + quad * 4 + r][0] = d0[i][r];
                    dred[cs][i * 16 + quad * 4 + r][1] = d1[i][r];
                }
        }
        __syncthreads();
        if (wv == 0 && lc == 0) {
            #pragma unroll
            for (int i = 0; i < 2; ++i)
                #pragma unroll
                for (int r = 0; r < 4; ++r) {
                    int row_l = i * 16 + quad * 4 + r;
                    float l0 = fm_s[row_l][0] + b3[0];
                    float l1 = fm_s[row_l][1] + b3[1];
                    #pragma unroll
                    for (int c = 0; c < 4; ++c) {
                        l0 += dred[c][row_l][0];
                        l1 += dred[c][row_l][1];
                    }
                    float mx = fmaxf(l0, l1);
                    float e0 = __expf(l0 - mx), e1 = __expf(l1 - mx);
                    float inv = 1.f / (e0 + e1);
                    *(float2*)(out + (size_t)(m0 + row_l) * 2) = (float2){e0 * inv, e1 * inv};
                }
        }
    }
}

extern "C" void kernel_launch(void* const* d_in, const int* in_sizes, int n_in,
                              void* d_out, int out_size, void* d_ws, size_t ws_size,
                              hipStream_t stream) {
    const int*   user_id   = (const int*)d_in[0];
    const int*   hour      = (const int*)d_in[1];
    const float* visual    = (const float*)d_in[2];
    const float* scale     = (const float*)d_in[3];
    const int*   gender    = (const int*)d_in[4];
    const int*   age       = (const int*)d_in[5];
    const int*   attribute = (const int*)d_in[6];
    const float* user_emb  = (const float*)d_in[7];
    const float* hour_emb  = (const float*)d_in[8];
    const float* gender_emb= (const float*)d_in[9];
    const float* age_emb   = (const float*)d_in[10];
    const float* attr_emb  = (const float*)d_in[11];
    const float* visu_w    = (const float*)d_in[12];
    const float* visu_b    = (const float*)d_in[13];
    const float* fm_w      = (const float*)d_in[14];
    const float* fm_b      = (const float*)d_in[15];
    const float* w1        = (const float*)d_in[16];
    const float* b1        = (const float*)d_in[17];
    const float* w2        = (const float*)d_in[18];
    const float* b2        = (const float*)d_in[19];
    const float* w3        = (const float*)d_in[20];
    const float* b3        = (const float*)d_in[21];
    float* out = (float*)d_out;

    // NO workspace use: weights are converted fp32->bf16 on the fly in registers.
    (void)d_ws; (void)ws_size;

    mega_kernel<<<BATCH / 32, 256, 0, stream>>>(
        user_id, hour, visual, scale, gender, age, attribute,
        user_emb, hour_emb, gender_emb, age_emb, attr_emb,
        visu_w, visu_b, fm_w, fm_b, w1, b1, w2, b2, w3, b3, out);
}

// Round 2
// 462.626 us; speedup vs baseline: 1.2274x; 1.2274x over previous
//
#include <hip/hip_runtime.h>
#include <hip/hip_bf16.h>
#include <stdint.h>

#define BATCH 16384
#define FACE_K 64
#define VISUAL_DIM 2048
#define HIDDEN 512
#define NUM_USERS 1000000
#define NUM_AGES 8
#define NUM_ATTR 40
#define VOCAB (NUM_USERS + 24 + 2 + NUM_AGES + NUM_ATTR)
#define XDIM 384
#define XS 388    // x-tile LDS stride (pad +4)
#define HS 516    // h1 LDS stride (pad +4)

typedef __bf16 bf16x8 __attribute__((ext_vector_type(8)));
typedef float f32x4 __attribute__((ext_vector_type(4)));

__device__ __forceinline__ uint16_t f2bf(float f) {
    union { float f; uint32_t u; } v; v.f = f;
    uint32_t r = v.u + 0x7fffu + ((v.u >> 16) & 1u);
    return (uint16_t)(r >> 16);
}

// fp32x8 -> bf16x8 in registers (for the visual A-operand)
__device__ __forceinline__ bf16x8 cvt8(float4 a, float4 b) {
    bf16x8 r;
    r[0] = (__bf16)a.x; r[1] = (__bf16)a.y; r[2] = (__bf16)a.z; r[3] = (__bf16)a.w;
    r[4] = (__bf16)b.x; r[5] = (__bf16)b.y; r[6] = (__bf16)b.z; r[7] = (__bf16)b.w;
    return r;
}

// ---------------- weight cast + fragment-order swizzle ----------------
// Writes vwb/w1b/w2b in MFMA B-fragment order: for each (frag), 64 lanes x 16B
// contiguous (1KB per fragment). Mega's weight loads become base + lane*16B:
// 16 cache lines per wave-load instead of 64, fully sequential streams.
//   vwb frag index: ((kh*32 + kk)*4 + j)          (kh<2, kk<32, j<4)
//   w1b frag index: ((cs*12 + ks)*8 + j)          (cs<4, ks<12, j<8)
//   w2b frag index: ((cs*16 + ks)*8 + j)          (cs<4, ks<16, j<8)
// lane slot holds w[col_base + j*16 + lc][k_base + quad*8 .. +8)
__global__ void cvt_frag(const float* __restrict__ visu_w, const float* __restrict__ w1,
                         const float* __restrict__ w2, uint16_t* __restrict__ vwb,
                         uint16_t* __restrict__ w1b, uint16_t* __restrict__ w2b) {
    int tid = blockIdx.x * blockDim.x + threadIdx.x;
    const float* src;
    uint16_t* dst;
    if (tid < 16384) {                       // visu_w: 64x2048
        int lane = tid & 63, fi = tid >> 6;
        int lc = lane & 15, quad = lane >> 4;
        int j = fi & 3, kk = (fi >> 2) & 31, kh = fi >> 7;
        src = visu_w + (size_t)(j * 16 + lc) * VISUAL_DIM + kh * 1024 + kk * 32 + quad * 8;
        dst = vwb + (size_t)tid * 8;
    } else if (tid < 40960) {                // w1: 512x384
        int t2 = tid - 16384;
        int lane = t2 & 63, fi = t2 >> 6;
        int lc = lane & 15, quad = lane >> 4;
        int j = fi & 7, csks = fi >> 3;
        int ks = csks % 12, cs = csks / 12;
        src = w1 + (size_t)(cs * 128 + j * 16 + lc) * XDIM + ks * 32 + quad * 8;
        dst = w1b + (size_t)t2 * 8;
    } else {                                 // w2: 512x512
        int t3 = tid - 40960;
        int lane = t3 & 63, fi = t3 >> 6;
        int lc = lane & 15, quad = lane >> 4;
        int j = fi & 7, csks = fi >> 3;
        int ks = csks & 15, cs = csks >> 4;
        src = w2 + (size_t)(cs * 128 + j * 16 + lc) * HIDDEN + ks * 32 + quad * 8;
        dst = w2b + (size_t)t3 * 8;
    }
    float4 a = *(const float4*)src;
    float4 b = *(const float4*)(src + 4);
    ushort4 o0, o1;
    o0.x = f2bf(a.x); o0.y = f2bf(a.y); o0.z = f2bf(a.z); o0.w = f2bf(a.w);
    o1.x = f2bf(b.x); o1.y = f2bf(b.y); o1.z = f2bf(b.z); o1.w = f2bf(b.w);
    *(ushort4*)dst = o0;
    *(ushort4*)(dst + 4) = o1;
}

// ---------------- mega-kernel: 32 rows per block, end-to-end ----------------
// 4 waves / block, grid = BATCH/32 = 512 blocks (2 blocks/CU)
__global__ __launch_bounds__(256) void mega_kernel(
        const int* __restrict__ uid, const int* __restrict__ hour,
        const float* __restrict__ visual, const float* __restrict__ scale,
        const int* __restrict__ gender, const int* __restrict__ age,
        const int* __restrict__ attr,
        const float* __restrict__ user_emb, const float* __restrict__ hour_emb,
        const float* __restrict__ gender_emb, const float* __restrict__ age_emb,
        const float* __restrict__ attr_emb,
        const uint16_t* __restrict__ vwb, const float* __restrict__ visu_b,
        const float* __restrict__ fm_w, const float* __restrict__ fm_b,
        const uint16_t* __restrict__ w1b, const float* __restrict__ b1,
        const uint16_t* __restrict__ w2b, const float* __restrict__ b2,
        const float* __restrict__ w3, const float* __restrict__ b3,
        float* __restrict__ out) {
    __shared__ uint16_t x_tile[32 * XS];
    __shared__ uint16_t h1s[32 * HS];
    __shared__ float red[2][16 * 64];
    __shared__ float fm_s[32][2];
    __shared__ float dred[4][32][2];

    int t = threadIdx.x;
    int wv = t >> 6, lane = t & 63;
    int lc = lane & 15, quad = lane >> 4;
    int m0 = blockIdx.x * 32;

    // ================= Phase E: embeddings + FM (wave -> 8 rows) =================
    {
        #pragma unroll 2
        for (int r8 = 0; r8 < 8; ++r8) {
            int row_l = wv * 8 + r8;
            int row_g = m0 + row_l;
            int u = uid[row_g], h = hour[row_g], g = gender[row_g];
            int a = age[row_g], at = attr[row_g];
            float sc = scale[row_g];
            float eu  = user_emb[(size_t)u * 64 + lane];
            float eh  = hour_emb[h * 64 + lane];
            float eg  = sc * tanhf(gender_emb[g * 64 + lane]);
            float eat = sc * tanhf(attr_emb[at * 64 + lane]);
            float eag = sc * tanhf(age_emb[a * 64 + lane]);
            float s  = eu + eh + eg + eat + eag;
            float sq = eu*eu + eh*eh + eg*eg + eat*eat + eag*eag;
            float so = s * s - sq;
            float l0 = 0.f, l1 = 0.f;
            if (lane < 5) {
                int col = (lane == 0) ? u
                        : (lane == 1) ? (NUM_USERS + h)
                        : (lane == 2) ? (NUM_USERS + 24 + g)
                        : (lane == 3) ? (NUM_USERS + 26 + a)
                        :               (NUM_USERS + 34 + at);
                l0 = fm_w[col];
                l1 = fm_w[VOCAB + col];
            }
            for (int m = 32; m; m >>= 1) {
                so += __shfl_xor(so, m);
                l0 += __shfl_xor(l0, m);
                l1 += __shfl_xor(l1, m);
            }
            if (lane == 0) {
                fm_s[row_l][0] = l0 + fm_b[0] + 0.5f * so;
                fm_s[row_l][1] = l1 + fm_b[1] + 0.5f * so;
            }
            int xb = row_l * XS;
            x_tile[xb +       lane] = f2bf(eu);
            x_tile[xb +  64 + lane] = f2bf(eh);
            x_tile[xb + 128 + lane] = f2bf(eg);
            x_tile[xb + 192 + lane] = f2bf(eat);
            x_tile[xb + 256 + lane] = f2bf(eag);
        }
    }

    // ================= Phase V: visual projection (wave = rg x kh) =================
    {
        int rg = wv >> 1, kh = wv & 1;
        const float*    va = visual + (size_t)(m0 + rg * 16 + lc) * VISUAL_DIM + kh * 1024 + quad * 8;
        const uint16_t* vb = vwb + (size_t)(kh * 32 * 4) * 512 + lane * 8;   // fragment stream

        f32x4 acc[4];
        #pragma unroll
        for (int j = 0; j < 4; ++j) acc[j] = (f32x4){0.f, 0.f, 0.f, 0.f};

        #pragma unroll 4
        for (int kk = 0; kk < 32; ++kk) {
            float4 a0 = *(const float4*)(va + kk * 32);
            float4 a1 = *(const float4*)(va + kk * 32 + 4);
            bf16x8 af = cvt8(a0, a1);
            #pragma unroll
            for (int j = 0; j < 4; ++j) {
                bf16x8 bf = *(const bf16x8*)(vb + (size_t)(kk * 4 + j) * 512);
                acc[j] = __builtin_amdgcn_mfma_f32_16x16x32_bf16(af, bf, acc[j], 0, 0, 0);
            }
        }
        if (kh == 1) {
            #pragma unroll
            for (int j = 0; j < 4; ++j)
                #pragma unroll
                for (int r = 0; r < 4; ++r)
                    red[rg][(quad * 4 + r) * 64 + j * 16 + lc] = acc[j][r];
        }
        __syncthreads();
        if (kh == 0) {
            #pragma unroll
            for (int j = 0; j < 4; ++j) {
                int col = j * 16 + lc;
                float b = visu_b[col];
                #pragma unroll
                for (int r = 0; r < 4; ++r) {
                    float sum = acc[j][r] + red[rg][(quad * 4 + r) * 64 + col] + b;
                    x_tile[(rg * 16 + quad * 4 + r) * XS + 320 + col] = f2bf(sum);
                }
            }
        }
    }
    __syncthreads();

    // ================= Phase 1: h1 = relu(x @ w1^T + b1), wave = col-quarter ======
    {
        int cs = wv;  // cols cs*128 .. cs*128+127
        const uint16_t* wp1 = w1b + (size_t)(cs * 12 * 8) * 512 + lane * 8;  // fragment stream
        const uint16_t* lp0 = x_tile + lc * XS + quad * 8;
        const uint16_t* lp1 = x_tile + (16 + lc) * XS + quad * 8;

        f32x4 acc[2][8];
        #pragma unroll
        for (int i = 0; i < 2; ++i)
            #pragma unroll
            for (int j = 0; j < 8; ++j) acc[i][j] = (f32x4){0.f, 0.f, 0.f, 0.f};

        #pragma unroll 2
        for (int ks = 0; ks < 12; ++ks) {
            union { bf16x8 v; ushort4 h[2]; } u0, u1;
            u0.h[0] = *(const ushort4*)(lp0 + ks * 32);
            u0.h[1] = *(const ushort4*)(lp0 + ks * 32 + 4);
            u1.h[0] = *(const ushort4*)(lp1 + ks * 32);
            u1.h[1] = *(const ushort4*)(lp1 + ks * 32 + 4);
            #pragma unroll
            for (int j = 0; j < 8; ++j) {
                bf16x8 bf = *(const bf16x8*)(wp1 + (size_t)(ks * 8 + j) * 512);
                acc[0][j] = __builtin_amdgcn_mfma_f32_16x16x32_bf16(u0.v, bf, acc[0][j], 0, 0, 0);
                acc[1][j] = __builtin_amdgcn_mfma_f32_16x16x32_bf16(u1.v, bf, acc[1][j], 0, 0, 0);
            }
        }
        #pragma unroll
        for (int j = 0; j < 8; ++j) {
            int col = cs * 128 + j * 16 + lc;
            float bb = b1[col];
            #pragma unroll
            for (int i = 0; i < 2; ++i)
                #pragma unroll
                for (int r = 0; r < 4; ++r) {
                    float v = fmaxf(acc[i][j][r] + bb, 0.f);
                    h1s[(i * 16 + quad * 4 + r) * HS + col] = f2bf(v);
                }
        }
    }
    __syncthreads();

    // ================= Phase 2: h2 cols + w3-dot + softmax =================
    {
        int cs = wv;
        const uint16_t* wp2 = w2b + (size_t)(cs * 16 * 8) * 512 + lane * 8;  // fragment stream
        const uint16_t* lp0 = h1s + lc * HS + quad * 8;
        const uint16_t* lp1 = h1s + (16 + lc) * HS + quad * 8;

        f32x4 acc[2][8];
        #pragma unroll
        for (int i = 0; i < 2; ++i)
            #pragma unroll
            for (int j = 0; j < 8; ++j) acc[i][j] = (f32x4){0.f, 0.f, 0.f, 0.f};

        #pragma unroll 2
        for (int ks = 0; ks < 16; ++ks) {
            union { bf16x8 v; ushort4 h[2]; } u0, u1;
            u0.h[0] = *(const ushort4*)(lp0 + ks * 32);
            u0.h[1] = *(const ushort4*)(lp0 + ks * 32 + 4);
            u1.h[0] = *(const ushort4*)(lp1 + ks * 32);
            u1.h[1] = *(const ushort4*)(lp1 + ks * 32 + 4);
            #pragma unroll
            for (int j = 0; j < 8; ++j) {
                bf16x8 bf = *(const bf16x8*)(wp2 + (size_t)(ks * 8 + j) * 512);
                acc[0][j] = __builtin_amdgcn_mfma_f32_16x16x32_bf16(u0.v, bf, acc[0][j], 0, 0, 0);
                acc[1][j] = __builtin_amdgcn_mfma_f32_16x16x32_bf16(u1.v, bf, acc[1][j], 0, 0, 0);
            }
        }
        // relu + b2, dot with w3 columns
        float d0[2][4] = {{0,0,0,0},{0,0,0,0}}, d1[2][4] = {{0,0,0,0},{0,0,0,0}};
        #pragma unroll
        for (int j = 0; j < 8; ++j) {
            int col = cs * 128 + j * 16 + lc;
            float bb = b2[col];
            float wa = w3[col], wb = w3[HIDDEN + col];
            #pragma unroll
            for (int i = 0; i < 2; ++i)
                #pragma unroll
                for (int r = 0; r < 4; ++r) {
                    float v = fmaxf(acc[i][j][r] + bb, 0.f);
                    d0[i][r] += v * wa;
                    d1[i][r] += v * wb;
                }
        }
        #pragma unroll
        for (int m = 1; m <= 8; m <<= 1) {
            #pragma unroll
            for (int i = 0; i < 2; ++i)
                #pragma unroll
                for (int r = 0; r < 4; ++r) {
                    d0[i][r] += __shfl_xor(d0[i][r], m);
                    d1[i][r] += __shfl_xor(d1[i][r], m);
                }
        }
        if (lc == 0) {
            #pragma unroll
            for (int i = 0; i < 2; ++i)
                #pragma unroll
                for (int r = 0; r < 4; ++r) {
                    dred[cs][i * 16 + quad * 4 + r][0] = d0[i][r];
                    dred[cs][i * 16 + quad * 4 + r][1] = d1[i][r];
                }
        }
        __syncthreads();
        if (wv == 0 && lc == 0) {
            #pragma unroll
            for (int i = 0; i < 2; ++i)
                #pragma unroll
                for (int r = 0; r < 4; ++r) {
                    int row_l = i * 16 + quad * 4 + r;
                    float l0 = fm_s[row_l][0] + b3[0];
                    float l1 = fm_s[row_l][1] + b3[1];
                    #pragma unroll
                    for (int c = 0; c < 4; ++c) {
                        l0 += dred[c][row_l][0];
                        l1 += dred[c][row_l][1];
                    }
                    float mx = fmaxf(l0, l1);
                    float e0 = __expf(l0 - mx), e1 = __expf(l1 - mx);
                    float inv = 1.f / (e0 + e1);
                    *(float2*)(out + (size_t)(m0 + row_l) * 2) = (float2){e0 * inv, e1 * inv};
                }
        }
    }
}

extern "C" void kernel_launch(void* const* d_in, const int* in_sizes, int n_in,
                              void* d_out, int out_size, void* d_ws, size_t ws_size,
                              hipStream_t stream) {
    const int*   user_id   = (const int*)d_in[0];
    const int*   hour      = (const int*)d_in[1];
    const float* visual    = (const float*)d_in[2];
    const float* scale     = (const float*)d_in[3];
    const int*   gender    = (const int*)d_in[4];
    const int*   age       = (const int*)d_in[5];
    const int*   attribute = (const int*)d_in[6];
    const float* user_emb  = (const float*)d_in[7];
    const float* hour_emb  = (const float*)d_in[8];
    const float* gender_emb= (const float*)d_in[9];
    const float* age_emb   = (const float*)d_in[10];
    const float* attr_emb  = (const float*)d_in[11];
    const float* visu_w    = (const float*)d_in[12];
    const float* visu_b    = (const float*)d_in[13];
    const float* fm_w      = (const float*)d_in[14];
    const float* fm_b      = (const float*)d_in[15];
    const float* w1        = (const float*)d_in[16];
    const float* b1        = (const float*)d_in[17];
    const float* w2        = (const float*)d_in[18];
    const float* b2        = (const float*)d_in[19];
    const float* w3        = (const float*)d_in[20];
    const float* b3        = (const float*)d_in[21];
    float* out = (float*)d_out;

    char* ws = (char*)d_ws;
    uint16_t* vwb = (uint16_t*)ws;            // 64*2048 u16  (fragment order)
    uint16_t* w1b = vwb + 64 * 2048;          // 512*384 u16  (fragment order)
    uint16_t* w2b = w1b + 512 * 384;          // 512*512 u16  (fragment order)

    cvt_frag<<<288, 256, 0, stream>>>(visu_w, w1, w2, vwb, w1b, w2b);
    mega_kernel<<<BATCH / 32, 256, 0, stream>>>(
        user_id, hour, visual, scale, gender, age, attribute,
        user_emb, hour_emb, gender_emb, age_emb, attr_emb,
        vwb, visu_b, fm_w, fm_b, w1b, b1, w2b, b2, w3, b3, out);
}

// Round 3
// 438.521 us; speedup vs baseline: 1.2949x; 1.0550x over previous
//
#include <hip/hip_runtime.h>
#include <hip/hip_bf16.h>
#include <stdint.h>

#define BATCH 16384
#define FACE_K 64
#define VISUAL_DIM 2048
#define HIDDEN 512
#define NUM_USERS 1000000
#define NUM_AGES 8
#define NUM_ATTR 40
#define VOCAB (NUM_USERS + 24 + 2 + NUM_AGES + NUM_ATTR)
#define XDIM 384
#define XS 388    // x-tile LDS stride (pad +4)
#define HS 516    // h1 LDS stride (pad +4)

typedef __bf16 bf16x8 __attribute__((ext_vector_type(8)));
typedef float f32x4 __attribute__((ext_vector_type(4)));

__device__ __forceinline__ uint16_t f2bf(float f) {
    union { float f; uint32_t u; } v; v.f = f;
    uint32_t r = v.u + 0x7fffu + ((v.u >> 16) & 1u);
    return (uint16_t)(r >> 16);
}

// fp32x8 -> bf16x8 in registers (for the visual A-operand)
__device__ __forceinline__ bf16x8 cvt8(float4 a, float4 b) {
    bf16x8 r;
    r[0] = (__bf16)a.x; r[1] = (__bf16)a.y; r[2] = (__bf16)a.z; r[3] = (__bf16)a.w;
    r[4] = (__bf16)b.x; r[5] = (__bf16)b.y; r[6] = (__bf16)b.z; r[7] = (__bf16)b.w;
    return r;
}

// ---------------- weight cast + fragment-order swizzle (unchanged layout) ----------------
//   vwb frag index: (kk_g*4 + j)            kk_g<64, j<4
//   w1b frag index: ((cs4*12 + ks)*8 + j)   cs4<4, ks<12, j<8
//   w2b frag index: ((cs4*16 + ks)*8 + j)   cs4<4, ks<16, j<8
// lane slot holds w[col_base + j*16 + lc][k_base + quad*8 .. +8)
__global__ void cvt_frag(const float* __restrict__ visu_w, const float* __restrict__ w1,
                         const float* __restrict__ w2, uint16_t* __restrict__ vwb,
                         uint16_t* __restrict__ w1b, uint16_t* __restrict__ w2b) {
    int tid = blockIdx.x * blockDim.x + threadIdx.x;
    const float* src;
    uint16_t* dst;
    if (tid < 16384) {                       // visu_w: 64x2048
        int lane = tid & 63, fi = tid >> 6;
        int lc = lane & 15, quad = lane >> 4;
        int j = fi & 3, kk = (fi >> 2) & 31, kh = fi >> 7;
        src = visu_w + (size_t)(j * 16 + lc) * VISUAL_DIM + kh * 1024 + kk * 32 + quad * 8;
        dst = vwb + (size_t)tid * 8;
    } else if (tid < 40960) {                // w1: 512x384
        int t2 = tid - 16384;
        int lane = t2 & 63, fi = t2 >> 6;
        int lc = lane & 15, quad = lane >> 4;
        int j = fi & 7, csks = fi >> 3;
        int ks = csks % 12, cs = csks / 12;
        src = w1 + (size_t)(cs * 128 + j * 16 + lc) * XDIM + ks * 32 + quad * 8;
        dst = w1b + (size_t)t2 * 8;
    } else {                                 // w2: 512x512
        int t3 = tid - 40960;
        int lane = t3 & 63, fi = t3 >> 6;
        int lc = lane & 15, quad = lane >> 4;
        int j = fi & 7, csks = fi >> 3;
        int ks = csks & 15, cs = csks >> 4;
        src = w2 + (size_t)(cs * 128 + j * 16 + lc) * HIDDEN + ks * 32 + quad * 8;
        dst = w2b + (size_t)t3 * 8;
    }
    float4 a = *(const float4*)src;
    float4 b = *(const float4*)(src + 4);
    ushort4 o0, o1;
    o0.x = f2bf(a.x); o0.y = f2bf(a.y); o0.z = f2bf(a.z); o0.w = f2bf(a.w);
    o1.x = f2bf(b.x); o1.y = f2bf(b.y); o1.z = f2bf(b.z); o1.w = f2bf(b.w);
    *(ushort4*)dst = o0;
    *(ushort4*)(dst + 4) = o1;
}

// ---------------- mega-kernel: 32 rows per block, 8 waves, end-to-end ----------------
// 8 waves / block (512 thr), grid = BATCH/32 = 512 blocks -> 2 blocks/CU, 4 waves/SIMD
__global__ __launch_bounds__(512, 4) void mega_kernel(
        const int* __restrict__ uid, const int* __restrict__ hour,
        const float* __restrict__ visual, const float* __restrict__ scale,
        const int* __restrict__ gender, const int* __restrict__ age,
        const int* __restrict__ attr,
        const float* __restrict__ user_emb, const float* __restrict__ hour_emb,
        const float* __restrict__ gender_emb, const float* __restrict__ age_emb,
        const float* __restrict__ attr_emb,
        const uint16_t* __restrict__ vwb, const float* __restrict__ visu_b,
        const float* __restrict__ fm_w, const float* __restrict__ fm_b,
        const uint16_t* __restrict__ w1b, const float* __restrict__ b1,
        const uint16_t* __restrict__ w2b, const float* __restrict__ b2,
        const float* __restrict__ w3, const float* __restrict__ b3,
        float* __restrict__ out) {
    // x_tile (24832 B) + red (24576 B) live E..V; h1s (33024 B) overlays both P1..P2
    __shared__ __align__(16) char smem[49408];
    uint16_t* x_tile = (uint16_t*)smem;              // 32 * XS u16
    float*    red    = (float*)(smem + 24832);       // 2 rg * 3 partials * 1024 f32
    uint16_t* h1s    = (uint16_t*)smem;              // 32 * HS u16 (overlay)
    __shared__ float fm_s[32][2];
    __shared__ float dred[8][32][2];

    int t = threadIdx.x;
    int wv = t >> 6, lane = t & 63;
    int lc = lane & 15, quad = lane >> 4;
    int m0 = blockIdx.x * 32;

    // ================= Phase E: embeddings + FM (wave -> 4 rows) =================
    {
        #pragma unroll 2
        for (int r4 = 0; r4 < 4; ++r4) {
            int row_l = wv * 4 + r4;
            int row_g = m0 + row_l;
            int u = uid[row_g], h = hour[row_g], g = gender[row_g];
            int a = age[row_g], at = attr[row_g];
            float sc = scale[row_g];
            float eu  = user_emb[(size_t)u * 64 + lane];
            float eh  = hour_emb[h * 64 + lane];
            float eg  = sc * tanhf(gender_emb[g * 64 + lane]);
            float eat = sc * tanhf(attr_emb[at * 64 + lane]);
            float eag = sc * tanhf(age_emb[a * 64 + lane]);
            float s  = eu + eh + eg + eat + eag;
            float sq = eu*eu + eh*eh + eg*eg + eat*eat + eag*eag;
            float so = s * s - sq;
            float l0 = 0.f, l1 = 0.f;
            if (lane < 5) {
                int col = (lane == 0) ? u
                        : (lane == 1) ? (NUM_USERS + h)
                        : (lane == 2) ? (NUM_USERS + 24 + g)
                        : (lane == 3) ? (NUM_USERS + 26 + a)
                        :               (NUM_USERS + 34 + at);
                l0 = fm_w[col];
                l1 = fm_w[VOCAB + col];
            }
            for (int m = 32; m; m >>= 1) {
                so += __shfl_xor(so, m);
                l0 += __shfl_xor(l0, m);
                l1 += __shfl_xor(l1, m);
            }
            if (lane == 0) {
                fm_s[row_l][0] = l0 + fm_b[0] + 0.5f * so;
                fm_s[row_l][1] = l1 + fm_b[1] + 0.5f * so;
            }
            int xb = row_l * XS;
            x_tile[xb +       lane] = f2bf(eu);
            x_tile[xb +  64 + lane] = f2bf(eh);
            x_tile[xb + 128 + lane] = f2bf(eg);
            x_tile[xb + 192 + lane] = f2bf(eat);
            x_tile[xb + 256 + lane] = f2bf(eag);
        }
    }

    // ======== Phase V: visual projection, wave = (rg, kh): rows rg*16, K-quarter kh ========
    {
        int rg = wv & 1, kh = wv >> 1;   // kh in 0..3, K range [kh*512, kh*512+512)
        const float*    va = visual + (size_t)(m0 + rg * 16 + lc) * VISUAL_DIM + kh * 512 + quad * 8;
        const uint16_t* vb = vwb + (size_t)(kh * 64) * 512 + lane * 8;   // fragment stream

        f32x4 acc[4];
        #pragma unroll
        for (int j = 0; j < 4; ++j) acc[j] = (f32x4){0.f, 0.f, 0.f, 0.f};

        #pragma unroll 4
        for (int kk = 0; kk < 16; ++kk) {
            float4 a0 = *(const float4*)(va + kk * 32);
            float4 a1 = *(const float4*)(va + kk * 32 + 4);
            bf16x8 af = cvt8(a0, a1);
            #pragma unroll
            for (int j = 0; j < 4; ++j) {
                bf16x8 bf = *(const bf16x8*)(vb + (size_t)(kk * 4 + j) * 512);
                acc[j] = __builtin_amdgcn_mfma_f32_16x16x32_bf16(af, bf, acc[j], 0, 0, 0);
            }
        }
        if (kh > 0) {
            float* base = red + (size_t)(rg * 3 + (kh - 1)) * 1024;
            #pragma unroll
            for (int j = 0; j < 4; ++j)
                #pragma unroll
                for (int r = 0; r < 4; ++r)
                    base[(quad * 4 + r) * 64 + j * 16 + lc] = acc[j][r];
        }
        __syncthreads();
        if (kh == 0) {
            const float* p0 = red + (size_t)(rg * 3 + 0) * 1024;
            const float* p1 = red + (size_t)(rg * 3 + 1) * 1024;
            const float* p2 = red + (size_t)(rg * 3 + 2) * 1024;
            #pragma unroll
            for (int j = 0; j < 4; ++j) {
                int col = j * 16 + lc;
                float b = visu_b[col];
                #pragma unroll
                for (int r = 0; r < 4; ++r) {
                    int e = (quad * 4 + r) * 64 + col;
                    float sum = acc[j][r] + p0[e] + p1[e] + p2[e] + b;
                    x_tile[(rg * 16 + quad * 4 + r) * XS + 320 + col] = f2bf(sum);
                }
            }
        }
    }
    __syncthreads();

    // ========= Phase 1: h1 = relu(x @ w1^T + b1), wave = 64-col slice =========
    {
        int cs = wv;  // cols cs*64 .. cs*64+63
        const uint16_t* wp1 = w1b + (size_t)((cs >> 1) * 96 + (cs & 1) * 4) * 512 + lane * 8;
        const uint16_t* lp0 = x_tile + lc * XS + quad * 8;
        const uint16_t* lp1 = x_tile + (16 + lc) * XS + quad * 8;

        f32x4 acc[2][4];
        #pragma unroll
        for (int i = 0; i < 2; ++i)
            #pragma unroll
            for (int j = 0; j < 4; ++j) acc[i][j] = (f32x4){0.f, 0.f, 0.f, 0.f};

        #pragma unroll 3
        for (int ks = 0; ks < 12; ++ks) {
            union { bf16x8 v; ushort4 h[2]; } u0, u1;
            u0.h[0] = *(const ushort4*)(lp0 + ks * 32);
            u0.h[1] = *(const ushort4*)(lp0 + ks * 32 + 4);
            u1.h[0] = *(const ushort4*)(lp1 + ks * 32);
            u1.h[1] = *(const ushort4*)(lp1 + ks * 32 + 4);
            #pragma unroll
            for (int j = 0; j < 4; ++j) {
                bf16x8 bf = *(const bf16x8*)(wp1 + (size_t)(ks * 8 + j) * 512);
                acc[0][j] = __builtin_amdgcn_mfma_f32_16x16x32_bf16(u0.v, bf, acc[0][j], 0, 0, 0);
                acc[1][j] = __builtin_amdgcn_mfma_f32_16x16x32_bf16(u1.v, bf, acc[1][j], 0, 0, 0);
            }
        }
        __syncthreads();   // all x_tile reads done before h1s overlays it
        #pragma unroll
        for (int j = 0; j < 4; ++j) {
            int col = cs * 64 + j * 16 + lc;
            float bb = b1[col];
            #pragma unroll
            for (int i = 0; i < 2; ++i)
                #pragma unroll
                for (int r = 0; r < 4; ++r) {
                    float v = fmaxf(acc[i][j][r] + bb, 0.f);
                    h1s[(i * 16 + quad * 4 + r) * HS + col] = f2bf(v);
                }
        }
    }
    __syncthreads();

    // ========= Phase 2: h2 64-col slice + w3-dot + softmax =========
    {
        int cs = wv;
        const uint16_t* wp2 = w2b + (size_t)((cs >> 1) * 128 + (cs & 1) * 4) * 512 + lane * 8;
        const uint16_t* lp0 = h1s + lc * HS + quad * 8;
        const uint16_t* lp1 = h1s + (16 + lc) * HS + quad * 8;

        f32x4 acc[2][4];
        #pragma unroll
        for (int i = 0; i < 2; ++i)
            #pragma unroll
            for (int j = 0; j < 4; ++j) acc[i][j] = (f32x4){0.f, 0.f, 0.f, 0.f};

        #pragma unroll 4
        for (int ks = 0; ks < 16; ++ks) {
            union { bf16x8 v; ushort4 h[2]; } u0, u1;
            u0.h[0] = *(const ushort4*)(lp0 + ks * 32);
            u0.h[1] = *(const ushort4*)(lp0 + ks * 32 + 4);
            u1.h[0] = *(const ushort4*)(lp1 + ks * 32);
            u1.h[1] = *(const ushort4*)(lp1 + ks * 32 + 4);
            #pragma unroll
            for (int j = 0; j < 4; ++j) {
                bf16x8 bf = *(const bf16x8*)(wp2 + (size_t)(ks * 8 + j) * 512);
                acc[0][j] = __builtin_amdgcn_mfma_f32_16x16x32_bf16(u0.v, bf, acc[0][j], 0, 0, 0);
                acc[1][j] = __builtin_amdgcn_mfma_f32_16x16x32_bf16(u1.v, bf, acc[1][j], 0, 0, 0);
            }
        }
        // relu + b2, dot with w3 columns
        float d0[2][4] = {{0,0,0,0},{0,0,0,0}}, d1[2][4] = {{0,0,0,0},{0,0,0,0}};
        #pragma unroll
        for (int j = 0; j < 4; ++j) {
            int col = cs * 64 + j * 16 + lc;
            float bb = b2[col];
            float wa = w3[col], wb = w3[HIDDEN + col];
            #pragma unroll
            for (int i = 0; i < 2; ++i)
                #pragma unroll
                for (int r = 0; r < 4; ++r) {
                    float v = fmaxf(acc[i][j][r] + bb, 0.f);
                    d0[i][r] += v * wa;
                    d1[i][r] += v * wb;
                }
        }
        #pragma unroll
        for (int m = 1; m <= 8; m <<= 1) {
            #pragma unroll
            for (int i = 0; i < 2; ++i)
                #pragma unroll
                for (int r = 0; r < 4; ++r) {
                    d0[i][r] += __shfl_xor(d0[i][r], m);
                    d1[i][r] += __shfl_xor(d1[i][r], m);
                }
        }
        if (lc == 0) {
            #pragma unroll
            for (int i = 0; i < 2; ++i)
                #pragma unroll
                for (int r = 0; r < 4; ++r) {
                    dred[cs][i * 16 + quad * 4 + r][0] = d0[i][r];
                    dred[cs][i * 16 + quad * 4 + r][1] = d1[i][r];
                }
        }
        __syncthreads();
        if (wv == 0 && lc == 0) {
            #pragma unroll
            for (int i = 0; i < 2; ++i)
                #pragma unroll
                for (int r = 0; r < 4; ++r) {
                    int row_l = i * 16 + quad * 4 + r;
                    float l0 = fm_s[row_l][0] + b3[0];
                    float l1 = fm_s[row_l][1] + b3[1];
                    #pragma unroll
                    for (int c = 0; c < 8; ++c) {
                        l0 += dred[c][row_l][0];
                        l1 += dred[c][row_l][1];
                    }
                    float mx = fmaxf(l0, l1);
                    float e0 = __expf(l0 - mx), e1 = __expf(l1 - mx);
                    float inv = 1.f / (e0 + e1);
                    *(float2*)(out + (size_t)(m0 + row_l) * 2) = (float2){e0 * inv, e1 * inv};
                }
        }
    }
}

extern "C" void kernel_launch(void* const* d_in, const int* in_sizes, int n_in,
                              void* d_out, int out_size, void* d_ws, size_t ws_size,
                              hipStream_t stream) {
    const int*   user_id   = (const int*)d_in[0];
    const int*   hour      = (const int*)d_in[1];
    const float* visual    = (const float*)d_in[2];
    const float* scale     = (const float*)d_in[3];
    const int*   gender    = (const int*)d_in[4];
    const int*   age       = (const int*)d_in[5];
    const int*   attribute = (const int*)d_in[6];
    const float* user_emb  = (const float*)d_in[7];
    const float* hour_emb  = (const float*)d_in[8];
    const float* gender_emb= (const float*)d_in[9];
    const float* age_emb   = (const float*)d_in[10];
    const float* attr_emb  = (const float*)d_in[11];
    const float* visu_w    = (const float*)d_in[12];
    const float* visu_b    = (const float*)d_in[13];
    const float* fm_w      = (const float*)d_in[14];
    const float* fm_b      = (const float*)d_in[15];
    const float* w1        = (const float*)d_in[16];
    const float* b1        = (const float*)d_in[17];
    const float* w2        = (const float*)d_in[18];
    const float* b2        = (const float*)d_in[19];
    const float* w3        = (const float*)d_in[20];
    const float* b3        = (const float*)d_in[21];
    float* out = (float*)d_out;

    char* ws = (char*)d_ws;
    uint16_t* vwb = (uint16_t*)ws;            // 64*2048 u16  (fragment order)
    uint16_t* w1b = vwb + 64 * 2048;          // 512*384 u16  (fragment order)
    uint16_t* w2b = w1b + 512 * 384;          // 512*512 u16  (fragment order)

    cvt_frag<<<288, 256, 0, stream>>>(visu_w, w1, w2, vwb, w1b, w2b);
    mega_kernel<<<BATCH / 32, 512, 0, stream>>>(
        user_id, hour, visual, scale, gender, age, attribute,
        user_emb, hour_emb, gender_emb, age_emb, attr_emb,
        vwb, visu_b, fm_w, fm_b, w1b, b1, w2b, b2, w3, b3, out);
}